// Round 4
// baseline (123.960 us; speedup 1.0000x reference)
//
#include <hip/hip_runtime.h>
#include <hip/hip_bf16.h>
#include <math.h>

// Problem constants
#define BATCH   4096
#define DIM     512
#define TWO_B   8192
#define INV_T   10.0f                       // 1/TEMP
#define LSE_SCALE 14.426950408889634f       // log2(e)/TEMP
#define NTILE   64                          // 8192 / 128
#define NTRI    2080                        // 64*65/2 upper-triangle tiles

typedef __attribute__((ext_vector_type(8)))  short bf16x8;   // 8 bf16 = 4 VGPRs
typedef __attribute__((ext_vector_type(16))) float floatx16; // 32x32 MFMA acc

#define AS1(p) ((__attribute__((address_space(1))) void*)(p))
#define AS3(p) ((__attribute__((address_space(3))) void*)(p))

static __device__ inline unsigned pack_bf2(float a, float b) {
    __hip_bfloat162 h2;
    h2.x = __float2bfloat16(a);
    h2.y = __float2bfloat16(b);
    return *(unsigned*)&h2;
}

// ---------------------------------------------------------------------------
// Kernel 1: L2-normalize pairs. One WAVE per pair (no barriers, no LDS).
// Each lane owns 8 columns (two float4 loads per input row).
// Grid: 1024 blocks x 256 threads = 4096 waves = 4096 pairs.
// ---------------------------------------------------------------------------
__global__ __launch_bounds__(256) void norm_kernel(
    const float* __restrict__ p1, const float* __restrict__ p2,
    __hip_bfloat16* __restrict__ z, float* __restrict__ pos)
{
    const int lane = threadIdx.x & 63;
    const int i = (blockIdx.x << 2) + (threadIdx.x >> 6);   // pair 0..4095

    const float4* xr = (const float4*)(p1 + (size_t)i * DIM);
    const float4* yr = (const float4*)(p2 + (size_t)i * DIM);
    const float4 x0 = xr[lane], x1 = xr[lane + 64];
    const float4 y0 = yr[lane], y1 = yr[lane + 64];

    const float xs[8] = {x0.x, x0.y, x0.z, x0.w, x1.x, x1.y, x1.z, x1.w};
    const float ys[8] = {y0.x, y0.y, y0.z, y0.w, y1.x, y1.y, y1.z, y1.w};

    float sx = 0.0f, sy = 0.0f, sd = 0.0f;
    #pragma unroll
    for (int j = 0; j < 8; ++j) {
        sx = fmaf(xs[j], xs[j], sx);
        sy = fmaf(ys[j], ys[j], sy);
        sd = fmaf(xs[j], ys[j], sd);
    }
    #pragma unroll
    for (int off = 1; off < 64; off <<= 1) {
        sx += __shfl_xor(sx, off, 64);
        sy += __shfl_xor(sy, off, 64);
        sd += __shfl_xor(sd, off, 64);
    }

    const float rx = 1.0f / fmaxf(sqrtf(sx), 1e-12f);
    const float ry = 1.0f / fmaxf(sqrtf(sy), 1e-12f);

    uint2 o0, o1, q0, q1;
    o0.x = pack_bf2(xs[0] * rx, xs[1] * rx);
    o0.y = pack_bf2(xs[2] * rx, xs[3] * rx);
    o1.x = pack_bf2(xs[4] * rx, xs[5] * rx);
    o1.y = pack_bf2(xs[6] * rx, xs[7] * rx);
    q0.x = pack_bf2(ys[0] * ry, ys[1] * ry);
    q0.y = pack_bf2(ys[2] * ry, ys[3] * ry);
    q1.x = pack_bf2(ys[4] * ry, ys[5] * ry);
    q1.y = pack_bf2(ys[6] * ry, ys[7] * ry);

    ((uint2*)(z + (size_t)i * DIM))[lane] = o0;                  // elems lane*4
    ((uint2*)(z + (size_t)i * DIM + 256))[lane] = o1;            // elems 256+lane*4
    ((uint2*)(z + (size_t)(i + BATCH) * DIM))[lane] = q0;
    ((uint2*)(z + (size_t)(i + BATCH) * DIM + 256))[lane] = q1;

    if (lane == 0) pos[i] = sd * rx * ry * INV_T;
}

// ---------------------------------------------------------------------------
// Kernel 2: UPPER-TRIANGLE fused z@z^T tiles. 32x32x16 bf16 MFMA, 128x128
// tile, BK=32, global_load_lds width=16, XOR-swizzled LDS. Each tile (rt,ct),
// rt<=ct, emits exp-sums both ways:
//   colsum_j -> partial[rt][ct*128+j]   (in-lane register adds)
//   rowsum_i -> partial[ct][rt*128+i]   (two-phase LDS transpose, 64 rows/ph)
// Diagonal tiles: colsums only; B staging skipped (A==B).
// LDS: 19,968 B (was 35,328) -> 8 blocks/CU by LDS; occupancy is the point.
// ---------------------------------------------------------------------------
__global__ __launch_bounds__(256) void sim_kernel(
    const __hip_bfloat16* __restrict__ z, float* __restrict__ partial)
{
    // Aliased phases:
    //   K-loop : As[128*32] bf16 (8 KB) | Bs[128*32] bf16 (8 KB) = floats [0,4096)
    //   epilogue: rowbuf[64][68] f32 = floats [0,4352) ; colred [4352,4992)
    __shared__ __align__(16) float smem_f[4992];              // 19,968 B
    __hip_bfloat16* As = (__hip_bfloat16*)smem_f;
    __hip_bfloat16* Bs = As + 128 * 32;
    float* rowbuf = smem_f;                    // [64][68]
    float* colred = smem_f + 4352;             // [128*5] — never aliases staging

    // --- triangular decode: blockIdx.x -> (rt, ct), rt <= ct --------------
    const int idx = blockIdx.x;
    int rt = (int)((129.0 - sqrt(16641.0 - 8.0 * (double)idx)) * 0.5);
    while (64 * (rt + 1) - ((rt + 1) * rt) / 2 <= idx) ++rt;
    while (64 * rt - (rt * (rt - 1)) / 2 > idx) --rt;
    const int ct = rt + (idx - (64 * rt - (rt * (rt - 1)) / 2));
    const bool diag = (rt == ct);

    const int t = threadIdx.x;
    const int wave = t >> 6, lane = t & 63;
    const int wr = wave >> 1, wc = wave & 1;   // 2x2 wave grid, 64x64 each
    const int lrow  = lane & 31;               // m/n within a 32-tile
    const int lhalf = lane >> 5;               // k-chunk selector

    const __hip_bfloat16* Ag = z + (size_t)rt * 128 * DIM;
    const __hip_bfloat16* Bg = z + (size_t)ct * 128 * DIM;
    const __hip_bfloat16* Bsrc = diag ? As : Bs;   // frag source for B

    floatx16 acc[2][2];
    #pragma unroll
    for (int mi = 0; mi < 2; ++mi)
        #pragma unroll
        for (int ni = 0; ni < 2; ++ni)
            acc[mi][ni] = (floatx16)0.0f;

    for (int k0 = 0; k0 < DIM; k0 += 32) {
        __syncthreads();   // previous iter's ds_reads done before overwrite
        #pragma unroll
        for (int i = 0; i < 2; ++i) {
            const int cidx = i * 256 + t;                  // 16B-chunk index
            const int row = cidx >> 2;                     // [128][32] tile row
            const int lch = (cidx & 3) ^ ((row >> 1) & 3); // logical chunk
            __builtin_amdgcn_global_load_lds(AS1(Ag + (size_t)row * DIM + k0 + lch * 8),
                                             AS3(As + i * 2048 + wave * 512),
                                             16, 0, 0);
            if (!diag)
                __builtin_amdgcn_global_load_lds(AS1(Bg + (size_t)row * DIM + k0 + lch * 8),
                                                 AS3(Bs + i * 2048 + wave * 512),
                                                 16, 0, 0);
        }
        __syncthreads();

        // A-frag (32x32x16): lane holds A[m = lane&31][k = (lane>>5)*8 + j].
        bf16x8 af[2][2], bf[2][2];
        #pragma unroll
        for (int mi = 0; mi < 2; ++mi)
            #pragma unroll
            for (int ks = 0; ks < 2; ++ks) {
                const int ch = ks * 2 + lhalf;
                const int rowA = wr * 64 + mi * 32 + lrow;
                const int pcA = ch ^ ((rowA >> 1) & 3);
                af[mi][ks] = *(const bf16x8*)(As + rowA * 32 + pcA * 8);
                const int rowB = wc * 64 + mi * 32 + lrow;
                const int pcB = ch ^ ((rowB >> 1) & 3);
                bf[mi][ks] = *(const bf16x8*)(Bsrc + rowB * 32 + pcB * 8);
            }

        #pragma unroll
        for (int ks = 0; ks < 2; ++ks)
            #pragma unroll
            for (int mi = 0; mi < 2; ++mi)
                #pragma unroll
                for (int ni = 0; ni < 2; ++ni)
                    acc[mi][ni] = __builtin_amdgcn_mfma_f32_32x32x16_bf16(
                        af[mi][ks], bf[ni][ks], acc[mi][ni], 0, 0, 0);
    }

    // --- epilogue ----------------------------------------------------------
    // C/D layout (m74/m101): col = lane&31,
    // row = (reg&3) + 8*(reg>>2) + 4*(lane>>5), within each 32x32 tile.
    float cs[2] = {0.0f, 0.0f};     // per-column sums (2 cols this lane owns)
    float rw[2][16];                // per-row partials (summed over ni in-lane)
    #pragma unroll
    for (int mi = 0; mi < 2; ++mi)
        #pragma unroll
        for (int r = 0; r < 16; ++r)
            rw[mi][r] = 0.0f;

    #pragma unroll
    for (int mi = 0; mi < 2; ++mi) {
        #pragma unroll
        for (int ni = 0; ni < 2; ++ni) {
            const int col_l = wc * 64 + ni * 32 + lrow;
            #pragma unroll
            for (int r = 0; r < 16; ++r) {
                const int row_l = wr * 64 + mi * 32 + lhalf * 4 + (r & 3) + 8 * (r >> 2);
                float ee = __builtin_amdgcn_exp2f(acc[mi][ni][r] * LSE_SCALE);
                if (diag && (row_l == col_l)) ee = 0.0f;   // -inf self mask
                cs[ni] += ee;
                rw[mi][r] += ee;
            }
        }
    }

    // col sums -> colred (4 partials/column, stride-5; no staging alias)
    const int slot = wr * 2 + lhalf;
    #pragma unroll
    for (int ni = 0; ni < 2; ++ni)
        colred[(wc * 64 + ni * 32 + lrow) * 5 + slot] = cs[ni];

    __syncthreads();   // K-loop ds_reads done (rowbuf aliasing) + colred visible

    if (t < 128) {
        const float s = colred[t * 5 + 0] + colred[t * 5 + 1] +
                        colred[t * 5 + 2] + colred[t * 5 + 3];
        partial[(size_t)rt * TWO_B + (size_t)ct * 128 + t] = s;
    }

    if (!diag) {
        #pragma unroll
        for (int p = 0; p < 2; ++p) {
            if (wr == p) {
                #pragma unroll
                for (int mi = 0; mi < 2; ++mi)
                    #pragma unroll
                    for (int r = 0; r < 16; ++r) {
                        const int lr = mi * 32 + lhalf * 4 + (r & 3) + 8 * (r >> 2);
                        rowbuf[lr * 68 + wc * 32 + lrow] = rw[mi][r];
                    }
            }
            __syncthreads();
            if (t < 128) {
                const int r = t >> 1, h = t & 1;
                const float4* rb = (const float4*)(rowbuf + r * 68 + h * 32);
                float s = 0.0f;
                #pragma unroll
                for (int j = 0; j < 8; ++j) {
                    const float4 v = rb[j];
                    s += (v.x + v.y) + (v.z + v.w);
                }
                s += __shfl_xor(s, 1, 64);     // combine the two half-rows
                if (h == 0)
                    partial[(size_t)ct * TWO_B + (size_t)rt * 128 + p * 64 + r] = s;
            }
            if (p == 0) __syncthreads();       // phase-0 reads before phase-1 writes
        }
    }
}

// ---------------------------------------------------------------------------
// Kernel 3: per-row sumexp over 64 tile contributions -> lse - pos term,
// block-reduced, atomically accumulated into out (final_kernel fused away).
// ---------------------------------------------------------------------------
__global__ __launch_bounds__(256) void lse_kernel(
    const float* __restrict__ partial, const float* __restrict__ pos,
    float* __restrict__ out)
{
    const int t = threadIdx.x;
    const int row = blockIdx.x * 256 + t;
    float s = 0.0f;
    #pragma unroll 8
    for (int tile = 0; tile < 64; ++tile)
        s += partial[(size_t)tile * TWO_B + row];
    float term = logf(s) - pos[row & (BATCH - 1)];   // sim_ij == sim_ji

    #pragma unroll
    for (int off = 32; off > 0; off >>= 1)
        term += __shfl_down(term, off);
    __shared__ float wsum[4];
    if ((t & 63) == 0) wsum[t >> 6] = term;
    __syncthreads();
    if (t == 0)
        atomicAdd(out, (wsum[0] + wsum[1] + wsum[2] + wsum[3]) *
                       (1.0f / (float)TWO_B));
}

// ---------------------------------------------------------------------------
extern "C" void kernel_launch(void* const* d_in, const int* in_sizes, int n_in,
                              void* d_out, int out_size, void* d_ws, size_t ws_size,
                              hipStream_t stream)
{
    const float* p1 = (const float*)d_in[0];
    const float* p2 = (const float*)d_in[1];
    float* out = (float*)d_out;

    // Workspace layout (all fully rewritten every call; poison-safe):
    //   z        : 8192*512 bf16  = 8,388,608 B
    //   pos      : 4096 f32       =    16,384 B
    //   partial  : 64*8192 f32    = 2,097,152 B
    char* ws = (char*)d_ws;
    __hip_bfloat16* z  = (__hip_bfloat16*)ws;
    float* pos         = (float*)(ws + 8388608);
    float* partial     = (float*)(ws + 8388608 + 16384);

    hipMemsetAsync(out, 0, sizeof(float), stream);   // atomic accumulator init
    norm_kernel<<<1024, 256, 0, stream>>>(p1, p2, z, pos);
    sim_kernel<<<NTRI, 256, 0, stream>>>(z, partial);
    lse_kernel<<<32, 256, 0, stream>>>(partial, pos, out);
}

// Round 5
// 102.291 us; speedup vs baseline: 1.2118x; 1.2118x over previous
//
#include <hip/hip_runtime.h>
#include <hip/hip_bf16.h>
#include <math.h>

// Problem constants
#define BATCH   4096
#define DIM     512
#define TWO_B   8192
#define INV_T   10.0f                       // 1/TEMP
#define LSE_SCALE 14.426950408889634f       // log2(e)/TEMP
#define NTRI    2080                        // 64*65/2 upper-triangle tiles

typedef __attribute__((ext_vector_type(8)))  int   intx8;    // 32 fp8 = 8 VGPRs
typedef __attribute__((ext_vector_type(4)))  int   intx4;
typedef __attribute__((ext_vector_type(16))) float floatx16; // 32x32 MFMA acc

#define AS1(p) ((__attribute__((address_space(1))) void*)(p))
#define AS3(p) ((__attribute__((address_space(3))) void*)(p))

// E8M0 scale byte: 2^(x-127). 123 -> 2^-4 per operand (z stored x16).
#define SCALE_E8M0 123

// ---------------------------------------------------------------------------
// Kernel 1: L2-normalize pairs; write z8 = fp8_e4m3(16 * z) and fp32
// pos[i] = cos(z_i, z_{i+B})/TEMP. Block-per-pair (round-3 form: it was the
// faster norm variant). Each thread owns 2 columns.
// ---------------------------------------------------------------------------
__global__ __launch_bounds__(256) void norm_kernel(
    const float* __restrict__ p1, const float* __restrict__ p2,
    unsigned char* __restrict__ z8, float* __restrict__ pos)
{
    const int i = blockIdx.x;          // 0..4095
    const int t = threadIdx.x;         // 0..255
    const int wave = t >> 6, lane = t & 63;

    const float2 xv = ((const float2*)(p1 + (size_t)i * DIM))[t];
    const float2 yv = ((const float2*)(p2 + (size_t)i * DIM))[t];

    float sx = fmaf(xv.x, xv.x, xv.y * xv.y);
    float sy = fmaf(yv.x, yv.x, yv.y * yv.y);
    float sd = fmaf(xv.x, yv.x, xv.y * yv.y);

    #pragma unroll
    for (int off = 32; off > 0; off >>= 1) {
        sx += __shfl_down(sx, off);
        sy += __shfl_down(sy, off);
        sd += __shfl_down(sd, off);
    }

    __shared__ float red[3][4];
    if (lane == 0) { red[0][wave] = sx; red[1][wave] = sy; red[2][wave] = sd; }
    __syncthreads();
    sx = red[0][0] + red[0][1] + red[0][2] + red[0][3];
    sy = red[1][0] + red[1][1] + red[1][2] + red[1][3];
    sd = red[2][0] + red[2][1] + red[2][2] + red[2][3];

    const float rx = 1.0f / fmaxf(sqrtf(sx), 1e-12f);
    const float ry = 1.0f / fmaxf(sqrtf(sy), 1e-12f);
    const float gx = 16.0f * rx, gy = 16.0f * ry;   // x16: avoid e4m3 subnormals

    const int px = __builtin_amdgcn_cvt_pk_fp8_f32(xv.x * gx, xv.y * gx, 0, false);
    const int py = __builtin_amdgcn_cvt_pk_fp8_f32(yv.x * gy, yv.y * gy, 0, false);
    ((unsigned short*)(z8 + (size_t)i * DIM))[t] = (unsigned short)px;
    ((unsigned short*)(z8 + (size_t)(i + BATCH) * DIM))[t] = (unsigned short)py;

    if (t == 0) pos[i] = sd * rx * ry * INV_T;
}

// ---------------------------------------------------------------------------
// Kernel 2: UPPER-TRIANGLE fused z@z^T tiles in MX-FP8.
// mfma_scale_f32_32x32x64_f8f6f4 (cbsz=blgp=0 -> e4m3), scale byte 123 both
// operands (2^-4 each; undoes the x16 z storage). 128x128 tile, BK=64,
// 8 K-iters, global_load_lds width=16.
//
// LDS tile layout (per tile: 128 rows x 64 B): 16B chunks, swizzled at
// row-pair granularity: physical p = (m>>1)*8 + (((m&1)*4 + c) ^ ((m>>1)&7)).
// Staging permutes the *global source* (dest must stay base+lane*16);
// frag reads (32 B/lane as 2x b128) are then conflict-free (4 words/bank).
//
// A/B frag layout (natural ext of verified 32x32x16): m = lane&31,
// k = (lane>>5)*32 + byte. C/D layout shape-determined (m121-128).
// Epilogue: exp2 + diag mask; colsum in-lane, rowsum via 2-phase LDS
// transpose; partial[rt][ct*128+j] and partial[ct][rt*128+i].
// ---------------------------------------------------------------------------
__global__ __launch_bounds__(256) void sim_kernel(
    const unsigned char* __restrict__ z8, float* __restrict__ partial)
{
    // Aliased phases:
    //   K-loop  : As 8 KB | Bs 8 KB                  = floats [0, 4096)
    //   epilogue: rowbuf[64][68] f32 floats [0,4352); colred [4352, 4992)
    __shared__ __align__(16) float smem_f[4992];              // 19,968 B
    unsigned char* As = (unsigned char*)smem_f;
    unsigned char* Bs = As + 8192;
    float* rowbuf = smem_f;                    // [64][68]
    float* colred = smem_f + 4352;             // [128*5]

    // --- triangular decode: blockIdx.x -> (rt, ct), rt <= ct --------------
    const int idx = blockIdx.x;
    int rt = (int)((129.0 - sqrt(16641.0 - 8.0 * (double)idx)) * 0.5);
    while (64 * (rt + 1) - ((rt + 1) * rt) / 2 <= idx) ++rt;
    while (64 * rt - (rt * (rt - 1)) / 2 > idx) --rt;
    const int ct = rt + (idx - (64 * rt - (rt * (rt - 1)) / 2));
    const bool diag = (rt == ct);

    const int t = threadIdx.x;
    const int wave = t >> 6, lane = t & 63;
    const int wr = wave >> 1, wc = wave & 1;   // 2x2 wave grid, 64x64 each
    const int lrow  = lane & 31;               // m/n within a 32-tile
    const int lhalf = lane >> 5;               // k-half selector

    const unsigned char* Ag = z8 + (size_t)rt * 128 * DIM;
    const unsigned char* Bg = z8 + (size_t)ct * 128 * DIM;
    const unsigned char* Bsrc = diag ? As : Bs;   // frag source for B

    // Staging source byte-offsets (loop-invariant): physical chunk
    // p = i*256 + t holds logical (row m, chunk c) per the swizzle inverse.
    int src_off[2];
    #pragma unroll
    for (int i = 0; i < 2; ++i) {
        const int p  = i * 256 + t;
        const int rp = p >> 3, h = p & 7;
        const int hl = h ^ (rp & 7);
        const int m  = rp * 2 + (hl >> 2);
        const int c  = hl & 3;
        src_off[i] = m * DIM + c * 16;
    }

    // Frag LDS byte-offsets (loop-invariant): lane needs row m, logical
    // chunks {lhalf*2, lhalf*2+1}.
    int offA[2][2], offB[2][2];
    #pragma unroll
    for (int mi = 0; mi < 2; ++mi)
        #pragma unroll
        for (int j = 0; j < 2; ++j) {
            const int c = lhalf * 2 + j;
            {
                const int m  = wr * 64 + mi * 32 + lrow;
                const int rp = m >> 1, hl = (m & 1) * 4 + c;
                offA[mi][j] = (rp * 8 + (hl ^ (rp & 7))) * 16;
            }
            {
                const int m  = wc * 64 + mi * 32 + lrow;
                const int rp = m >> 1, hl = (m & 1) * 4 + c;
                offB[mi][j] = (rp * 8 + (hl ^ (rp & 7))) * 16;
            }
        }

    floatx16 acc[2][2];
    #pragma unroll
    for (int mi = 0; mi < 2; ++mi)
        #pragma unroll
        for (int ni = 0; ni < 2; ++ni)
            acc[mi][ni] = (floatx16)0.0f;

    for (int k0 = 0; k0 < DIM; k0 += 64) {
        __syncthreads();   // previous iter's ds_reads done before overwrite
        #pragma unroll
        for (int i = 0; i < 2; ++i) {
            __builtin_amdgcn_global_load_lds(AS1(Ag + k0 + src_off[i]),
                                             AS3(As + i * 4096 + wave * 1024),
                                             16, 0, 0);
            if (!diag)
                __builtin_amdgcn_global_load_lds(AS1(Bg + k0 + src_off[i]),
                                                 AS3(Bs + i * 4096 + wave * 1024),
                                                 16, 0, 0);
        }
        __syncthreads();

        intx8 af[2], bf[2];
        #pragma unroll
        for (int mi = 0; mi < 2; ++mi) {
            const intx4 a0 = *(const intx4*)(As + offA[mi][0]);
            const intx4 a1 = *(const intx4*)(As + offA[mi][1]);
            const intx4 b0 = *(const intx4*)(Bsrc + offB[mi][0]);
            const intx4 b1 = *(const intx4*)(Bsrc + offB[mi][1]);
            #pragma unroll
            for (int j = 0; j < 4; ++j) {
                af[mi][j] = a0[j]; af[mi][j + 4] = a1[j];
                bf[mi][j] = b0[j]; bf[mi][j + 4] = b1[j];
            }
        }

        #pragma unroll
        for (int mi = 0; mi < 2; ++mi)
            #pragma unroll
            for (int ni = 0; ni < 2; ++ni)
                acc[mi][ni] = __builtin_amdgcn_mfma_scale_f32_32x32x64_f8f6f4(
                    af[mi], bf[ni], acc[mi][ni],
                    0, 0,                       // cbsz=fp8(e4m3), blgp=fp8(e4m3)
                    0, SCALE_E8M0,              // opsel_a, scale_a (2^-4)
                    0, SCALE_E8M0);             // opsel_b, scale_b (2^-4)
    }

    // --- epilogue ----------------------------------------------------------
    // C/D layout (shape-determined, m74/m101/m121-128): col = lane&31,
    // row = (reg&3) + 8*(reg>>2) + 4*(lane>>5), within each 32x32 tile.
    float cs[2] = {0.0f, 0.0f};     // per-column sums (2 cols this lane owns)
    float rw[2][16];                // per-row partials (summed over ni in-lane)
    #pragma unroll
    for (int mi = 0; mi < 2; ++mi)
        #pragma unroll
        for (int r = 0; r < 16; ++r)
            rw[mi][r] = 0.0f;

    #pragma unroll
    for (int mi = 0; mi < 2; ++mi) {
        #pragma unroll
        for (int ni = 0; ni < 2; ++ni) {
            const int col_l = wc * 64 + ni * 32 + lrow;
            #pragma unroll
            for (int r = 0; r < 16; ++r) {
                const int row_l = wr * 64 + mi * 32 + lhalf * 4 + (r & 3) + 8 * (r >> 2);
                float ee = __builtin_amdgcn_exp2f(acc[mi][ni][r] * LSE_SCALE);
                if (diag && (row_l == col_l)) ee = 0.0f;   // -inf self mask
                cs[ni] += ee;
                rw[mi][r] += ee;
            }
        }
    }

    // col sums -> colred (4 partials/column, stride-5; no staging alias)
    const int slot = wr * 2 + lhalf;
    #pragma unroll
    for (int ni = 0; ni < 2; ++ni)
        colred[(wc * 64 + ni * 32 + lrow) * 5 + slot] = cs[ni];

    __syncthreads();   // K-loop ds_reads done (rowbuf aliasing) + colred visible

    if (t < 128) {
        const float s = colred[t * 5 + 0] + colred[t * 5 + 1] +
                        colred[t * 5 + 2] + colred[t * 5 + 3];
        partial[(size_t)rt * TWO_B + (size_t)ct * 128 + t] = s;
    }

    if (!diag) {
        #pragma unroll
        for (int p = 0; p < 2; ++p) {
            if (wr == p) {
                #pragma unroll
                for (int mi = 0; mi < 2; ++mi)
                    #pragma unroll
                    for (int r = 0; r < 16; ++r) {
                        const int lr = mi * 32 + lhalf * 4 + (r & 3) + 8 * (r >> 2);
                        rowbuf[lr * 68 + wc * 32 + lrow] = rw[mi][r];
                    }
            }
            __syncthreads();
            if (t < 128) {
                const int r = t >> 1, h = t & 1;
                const float4* rb = (const float4*)(rowbuf + r * 68 + h * 32);
                float s = 0.0f;
                #pragma unroll
                for (int j = 0; j < 8; ++j) {
                    const float4 v = rb[j];
                    s += (v.x + v.y) + (v.z + v.w);
                }
                s += __shfl_xor(s, 1, 64);     // combine the two half-rows
                if (h == 0)
                    partial[(size_t)ct * TWO_B + (size_t)rt * 128 + p * 64 + r] = s;
            }
            if (p == 0) __syncthreads();       // phase-0 reads before phase-1 writes
        }
    }
}

// ---------------------------------------------------------------------------
// Kernel 3: per-row sumexp over 64 tile contributions -> lse - pos term,
// block-reduced, atomically accumulated into out.
// ---------------------------------------------------------------------------
__global__ __launch_bounds__(256) void lse_kernel(
    const float* __restrict__ partial, const float* __restrict__ pos,
    float* __restrict__ out)
{
    const int t = threadIdx.x;
    const int row = blockIdx.x * 256 + t;
    float s = 0.0f;
    #pragma unroll 8
    for (int tile = 0; tile < 64; ++tile)
        s += partial[(size_t)tile * TWO_B + row];
    float term = logf(s) - pos[row & (BATCH - 1)];   // sim_ij == sim_ji

    #pragma unroll
    for (int off = 32; off > 0; off >>= 1)
        term += __shfl_down(term, off);
    __shared__ float wsum[4];
    if ((t & 63) == 0) wsum[t >> 6] = term;
    __syncthreads();
    if (t == 0)
        atomicAdd(out, (wsum[0] + wsum[1] + wsum[2] + wsum[3]) *
                       (1.0f / (float)TWO_B));
}

// ---------------------------------------------------------------------------
extern "C" void kernel_launch(void* const* d_in, const int* in_sizes, int n_in,
                              void* d_out, int out_size, void* d_ws, size_t ws_size,
                              hipStream_t stream)
{
    const float* p1 = (const float*)d_in[0];
    const float* p2 = (const float*)d_in[1];
    float* out = (float*)d_out;

    // Workspace layout (all fully rewritten every call; poison-safe):
    //   z8       : 8192*512 fp8   = 4,194,304 B
    //   pos      : 4096 f32       =    16,384 B
    //   partial  : 64*8192 f32    = 2,097,152 B
    char* ws = (char*)d_ws;
    unsigned char* z8  = (unsigned char*)ws;
    float* pos         = (float*)(ws + 4194304);
    float* partial     = (float*)(ws + 4194304 + 16384);

    hipMemsetAsync(out, 0, sizeof(float), stream);   // atomic accumulator init
    norm_kernel<<<BATCH, 256, 0, stream>>>(p1, p2, z8, pos);
    sim_kernel<<<NTRI, 256, 0, stream>>>(z8, partial);
    lse_kernel<<<32, 256, 0, stream>>>(partial, pos, out);
}

// Round 6
// 99.511 us; speedup vs baseline: 1.2457x; 1.0279x over previous
//
#include <hip/hip_runtime.h>
#include <hip/hip_bf16.h>
#include <math.h>

// Problem constants
#define BATCH   4096
#define DIM     512
#define TWO_B   8192
#define INV_T   10.0f                       // 1/TEMP
#define LSE_SCALE 14.426950408889634f       // log2(e)/TEMP
#define NTRI    2080                        // 64*65/2 upper-triangle tiles

typedef __attribute__((ext_vector_type(8)))  int   intx8;    // 32 fp8 = 8 VGPRs
typedef __attribute__((ext_vector_type(4)))  int   intx4;
typedef __attribute__((ext_vector_type(16))) float floatx16; // 32x32 MFMA acc

#define AS1(p) ((__attribute__((address_space(1))) void*)(p))
#define AS3(p) ((__attribute__((address_space(3))) void*)(p))

// E8M0 scale byte: 2^(x-127). 123 -> 2^-4 per operand (z stored x16).
#define SCALE_E8M0 123

// ---------------------------------------------------------------------------
// Kernel 1: L2-normalize pairs; write z8 = fp8_e4m3(16 * z) and fp32
// pos[i] = cos(z_i, z_{i+B})/TEMP. Block-per-pair. Also zeroes out[0]
// (stream-ordered before lse_kernel's atomicAdd accumulation).
// ---------------------------------------------------------------------------
__global__ __launch_bounds__(256) void norm_kernel(
    const float* __restrict__ p1, const float* __restrict__ p2,
    unsigned char* __restrict__ z8, float* __restrict__ pos,
    float* __restrict__ out)
{
    const int i = blockIdx.x;          // 0..4095
    const int t = threadIdx.x;         // 0..255
    const int wave = t >> 6, lane = t & 63;

    if (i == 0 && t == 0) out[0] = 0.0f;   // atomic accumulator init

    const float2 xv = ((const float2*)(p1 + (size_t)i * DIM))[t];
    const float2 yv = ((const float2*)(p2 + (size_t)i * DIM))[t];

    float sx = fmaf(xv.x, xv.x, xv.y * xv.y);
    float sy = fmaf(yv.x, yv.x, yv.y * yv.y);
    float sd = fmaf(xv.x, yv.x, xv.y * yv.y);

    #pragma unroll
    for (int off = 32; off > 0; off >>= 1) {
        sx += __shfl_down(sx, off);
        sy += __shfl_down(sy, off);
        sd += __shfl_down(sd, off);
    }

    __shared__ float red[3][4];
    if (lane == 0) { red[0][wave] = sx; red[1][wave] = sy; red[2][wave] = sd; }
    __syncthreads();
    sx = red[0][0] + red[0][1] + red[0][2] + red[0][3];
    sy = red[1][0] + red[1][1] + red[1][2] + red[1][3];
    sd = red[2][0] + red[2][1] + red[2][2] + red[2][3];

    const float rx = 1.0f / fmaxf(sqrtf(sx), 1e-12f);
    const float ry = 1.0f / fmaxf(sqrtf(sy), 1e-12f);
    const float gx = 16.0f * rx, gy = 16.0f * ry;   // x16: avoid e4m3 subnormals

    const int px = __builtin_amdgcn_cvt_pk_fp8_f32(xv.x * gx, xv.y * gx, 0, false);
    const int py = __builtin_amdgcn_cvt_pk_fp8_f32(yv.x * gy, yv.y * gy, 0, false);
    ((unsigned short*)(z8 + (size_t)i * DIM))[t] = (unsigned short)px;
    ((unsigned short*)(z8 + (size_t)(i + BATCH) * DIM))[t] = (unsigned short)py;

    if (t == 0) pos[i] = sd * rx * ry * INV_T;
}

// ---------------------------------------------------------------------------
// Kernel 2: UPPER-TRIANGLE fused z@z^T tiles in MX-FP8, DOUBLE-BUFFERED LDS.
// mfma_scale_f32_32x32x64_f8f6f4, scale 2^-4 both operands. 128x128 tile,
// BK=64, 8 K-iters, ONE barrier per iter:
//   barrier -> issue stage of buf[(k+1)&1] (async, drained only at the NEXT
//   barrier, i.e. after a full compute phase) -> frag reads + MFMA on buf[k&1].
// LDS: 2 x (As 8K | Bs 8K) = 32 KB staging + colred 2.5 KB = 35,328 B.
// Swizzle: physical 16B-chunk p = (m>>1)*8 + (((m&1)*4 + c) ^ ((m>>1)&7)).
// Diagonal tiles stage A only (B frags read from As).
// Epilogue: exp2 + diag mask; colsum in-lane, rowsum via 2-phase transpose
// in rowbuf (aliases buf0); partial[rt][ct*128+j] and partial[ct][rt*128+i].
// ---------------------------------------------------------------------------
__global__ __launch_bounds__(256) void sim_kernel(
    const unsigned char* __restrict__ z8, float* __restrict__ partial)
{
    __shared__ __align__(16) unsigned char smem[35328];
    float* rowbuf = (float*)smem;              // [64][68] f32, aliases buf0
    float* colred = (float*)(smem + 32768);    // [128*5] f32, no alias

    // --- triangular decode: blockIdx.x -> (rt, ct), rt <= ct --------------
    const int idx = blockIdx.x;
    int rt = (int)((129.0 - sqrt(16641.0 - 8.0 * (double)idx)) * 0.5);
    while (64 * (rt + 1) - ((rt + 1) * rt) / 2 <= idx) ++rt;
    while (64 * rt - (rt * (rt - 1)) / 2 > idx) --rt;
    const int ct = rt + (idx - (64 * rt - (rt * (rt - 1)) / 2));
    const bool diag = (rt == ct);

    const int t = threadIdx.x;
    const int wave = t >> 6, lane = t & 63;
    const int wr = wave >> 1, wc = wave & 1;   // 2x2 wave grid, 64x64 each
    const int lrow  = lane & 31;               // m/n within a 32-tile
    const int lhalf = lane >> 5;               // k-half selector

    const unsigned char* Ag = z8 + (size_t)rt * 128 * DIM;
    const unsigned char* Bg = z8 + (size_t)ct * 128 * DIM;

    // Staging source byte-offsets (loop-invariant): physical chunk
    // p = i*256 + t holds logical (row m, chunk c) per the swizzle inverse.
    int src_off[2];
    #pragma unroll
    for (int i = 0; i < 2; ++i) {
        const int p  = i * 256 + t;
        const int rp = p >> 3, h = p & 7;
        const int hl = h ^ (rp & 7);
        const int m  = rp * 2 + (hl >> 2);
        const int c  = hl & 3;
        src_off[i] = m * DIM + c * 16;
    }

    // Frag LDS byte-offsets within a buffer (loop-invariant).
    int offA[2][2], offB[2][2];
    #pragma unroll
    for (int mi = 0; mi < 2; ++mi)
        #pragma unroll
        for (int j = 0; j < 2; ++j) {
            const int c = lhalf * 2 + j;
            {
                const int m  = wr * 64 + mi * 32 + lrow;
                const int rp = m >> 1, hl = (m & 1) * 4 + c;
                offA[mi][j] = (rp * 8 + (hl ^ (rp & 7))) * 16;
            }
            {
                const int m  = wc * 64 + mi * 32 + lrow;
                const int rp = m >> 1, hl = (m & 1) * 4 + c;
                offB[mi][j] = (rp * 8 + (hl ^ (rp & 7))) * 16;
            }
        }

    floatx16 acc[2][2];
    #pragma unroll
    for (int mi = 0; mi < 2; ++mi)
        #pragma unroll
        for (int ni = 0; ni < 2; ++ni)
            acc[mi][ni] = (floatx16)0.0f;

    // Prologue: stage k=0 into buffer 0 (drained by the k=0 barrier).
    {
        unsigned char* dst = smem + wave * 1024;
        #pragma unroll
        for (int i = 0; i < 2; ++i) {
            __builtin_amdgcn_global_load_lds(AS1(Ag + src_off[i]),
                                             AS3(dst + i * 4096), 16, 0, 0);
            if (!diag)
                __builtin_amdgcn_global_load_lds(AS1(Bg + src_off[i]),
                                                 AS3(dst + 8192 + i * 4096), 16, 0, 0);
        }
    }

    for (int k = 0; k < 8; ++k) {
        __syncthreads();   // drains stage of buf[k&1]; WAR-protects buf[(k+1)&1]

        if (k < 7) {       // prefetch next K-slab; in flight during this MFMA phase
            unsigned char* dst = smem + ((k + 1) & 1) * 16384 + wave * 1024;
            const int k1 = (k + 1) * 64;
            #pragma unroll
            for (int i = 0; i < 2; ++i) {
                __builtin_amdgcn_global_load_lds(AS1(Ag + k1 + src_off[i]),
                                                 AS3(dst + i * 4096), 16, 0, 0);
                if (!diag)
                    __builtin_amdgcn_global_load_lds(AS1(Bg + k1 + src_off[i]),
                                                     AS3(dst + 8192 + i * 4096), 16, 0, 0);
            }
        }

        const unsigned char* Ab = smem + (k & 1) * 16384;
        const unsigned char* Bb = diag ? Ab : Ab + 8192;

        intx8 af[2], bf[2];
        #pragma unroll
        for (int mi = 0; mi < 2; ++mi) {
            const intx4 a0 = *(const intx4*)(Ab + offA[mi][0]);
            const intx4 a1 = *(const intx4*)(Ab + offA[mi][1]);
            const intx4 b0 = *(const intx4*)(Bb + offB[mi][0]);
            const intx4 b1 = *(const intx4*)(Bb + offB[mi][1]);
            #pragma unroll
            for (int j = 0; j < 4; ++j) {
                af[mi][j] = a0[j]; af[mi][j + 4] = a1[j];
                bf[mi][j] = b0[j]; bf[mi][j + 4] = b1[j];
            }
        }

        #pragma unroll
        for (int mi = 0; mi < 2; ++mi)
            #pragma unroll
            for (int ni = 0; ni < 2; ++ni)
                acc[mi][ni] = __builtin_amdgcn_mfma_scale_f32_32x32x64_f8f6f4(
                    af[mi], bf[ni], acc[mi][ni],
                    0, 0,                       // cbsz=fp8(e4m3), blgp=fp8(e4m3)
                    0, SCALE_E8M0,              // opsel_a, scale_a (2^-4)
                    0, SCALE_E8M0);             // opsel_b, scale_b (2^-4)
    }

    // --- epilogue ----------------------------------------------------------
    // C/D layout (shape-determined, m74/m101/m121-128): col = lane&31,
    // row = (reg&3) + 8*(reg>>2) + 4*(lane>>5), within each 32x32 tile.
    float cs[2] = {0.0f, 0.0f};     // per-column sums (2 cols this lane owns)
    float rw[2][16];                // per-row partials (summed over ni in-lane)
    #pragma unroll
    for (int mi = 0; mi < 2; ++mi)
        #pragma unroll
        for (int r = 0; r < 16; ++r)
            rw[mi][r] = 0.0f;

    #pragma unroll
    for (int mi = 0; mi < 2; ++mi) {
        #pragma unroll
        for (int ni = 0; ni < 2; ++ni) {
            const int col_l = wc * 64 + ni * 32 + lrow;
            #pragma unroll
            for (int r = 0; r < 16; ++r) {
                const int row_l = wr * 64 + mi * 32 + lhalf * 4 + (r & 3) + 8 * (r >> 2);
                float ee = __builtin_amdgcn_exp2f(acc[mi][ni][r] * LSE_SCALE);
                if (diag && (row_l == col_l)) ee = 0.0f;   // -inf self mask
                cs[ni] += ee;
                rw[mi][r] += ee;
            }
        }
    }

    // col sums -> colred (4 partials/column, stride-5; no staging alias)
    const int slot = wr * 2 + lhalf;
    #pragma unroll
    for (int ni = 0; ni < 2; ++ni)
        colred[(wc * 64 + ni * 32 + lrow) * 5 + slot] = cs[ni];

    __syncthreads();   // K-loop ds_reads done (rowbuf aliasing) + colred visible

    if (t < 128) {
        const float s = colred[t * 5 + 0] + colred[t * 5 + 1] +
                        colred[t * 5 + 2] + colred[t * 5 + 3];
        partial[(size_t)rt * TWO_B + (size_t)ct * 128 + t] = s;
    }

    if (!diag) {
        #pragma unroll
        for (int p = 0; p < 2; ++p) {
            if (wr == p) {
                #pragma unroll
                for (int mi = 0; mi < 2; ++mi)
                    #pragma unroll
                    for (int r = 0; r < 16; ++r) {
                        const int lr = mi * 32 + lhalf * 4 + (r & 3) + 8 * (r >> 2);
                        rowbuf[lr * 68 + wc * 32 + lrow] = rw[mi][r];
                    }
            }
            __syncthreads();
            if (t < 128) {
                const int r = t >> 1, h = t & 1;
                const float4* rb = (const float4*)(rowbuf + r * 68 + h * 32);
                float s = 0.0f;
                #pragma unroll
                for (int j = 0; j < 8; ++j) {
                    const float4 v = rb[j];
                    s += (v.x + v.y) + (v.z + v.w);
                }
                s += __shfl_xor(s, 1, 64);     // combine the two half-rows
                if (h == 0)
                    partial[(size_t)ct * TWO_B + (size_t)rt * 128 + p * 64 + r] = s;
            }
            if (p == 0) __syncthreads();       // phase-0 reads before phase-1 writes
        }
    }
}

// ---------------------------------------------------------------------------
// Kernel 3: per-row sumexp over 64 tile contributions -> lse - pos term,
// block-reduced, atomically accumulated into out.
// ---------------------------------------------------------------------------
__global__ __launch_bounds__(256) void lse_kernel(
    const float* __restrict__ partial, const float* __restrict__ pos,
    float* __restrict__ out)
{
    const int t = threadIdx.x;
    const int row = blockIdx.x * 256 + t;
    float s = 0.0f;
    #pragma unroll 8
    for (int tile = 0; tile < 64; ++tile)
        s += partial[(size_t)tile * TWO_B + row];
    float term = logf(s) - pos[row & (BATCH - 1)];   // sim_ij == sim_ji

    #pragma unroll
    for (int off = 32; off > 0; off >>= 1)
        term += __shfl_down(term, off);
    __shared__ float wsum[4];
    if ((t & 63) == 0) wsum[t >> 6] = term;
    __syncthreads();
    if (t == 0)
        atomicAdd(out, (wsum[0] + wsum[1] + wsum[2] + wsum[3]) *
                       (1.0f / (float)TWO_B));
}

// ---------------------------------------------------------------------------
extern "C" void kernel_launch(void* const* d_in, const int* in_sizes, int n_in,
                              void* d_out, int out_size, void* d_ws, size_t ws_size,
                              hipStream_t stream)
{
    const float* p1 = (const float*)d_in[0];
    const float* p2 = (const float*)d_in[1];
    float* out = (float*)d_out;

    // Workspace layout (all fully rewritten every call; poison-safe):
    //   z8       : 8192*512 fp8   = 4,194,304 B
    //   pos      : 4096 f32       =    16,384 B
    //   partial  : 64*8192 f32    = 2,097,152 B
    char* ws = (char*)d_ws;
    unsigned char* z8  = (unsigned char*)ws;
    float* pos         = (float*)(ws + 4194304);
    float* partial     = (float*)(ws + 4194304 + 16384);

    norm_kernel<<<BATCH, 256, 0, stream>>>(p1, p2, z8, pos, out);
    sim_kernel<<<NTRI, 256, 0, stream>>>(z8, partial);
    lse_kernel<<<32, 256, 0, stream>>>(partial, pos, out);
}

// Round 7
// 98.111 us; speedup vs baseline: 1.2635x; 1.0143x over previous
//
#include <hip/hip_runtime.h>
#include <hip/hip_bf16.h>
#include <math.h>

// Problem constants
#define BATCH   4096
#define DIM     512
#define DIMB    256                         // bytes per z4 row (fp4 = nibble)
#define TWO_B   8192
#define INV_T   10.0f                       // 1/TEMP
#define LSE_SCALE 14.426950408889634f       // log2(e)/TEMP
#define NTRI    2080                        // 64*65/2 upper-triangle tiles

typedef __attribute__((ext_vector_type(8)))  int   intx8;
typedef __attribute__((ext_vector_type(4)))  int   intx4;
typedef __attribute__((ext_vector_type(16))) float floatx16; // 32x32 MFMA acc

#define AS1(p) ((__attribute__((address_space(1))) void*)(p))
#define AS3(p) ((__attribute__((address_space(3))) void*)(p))

// E8M0 scale byte: 2^(x-127). 122 -> 2^-5 per operand (z stored x32; 2^-10
// total undoes 32*32).
#define SCALE_E8M0 122
#define FMT_FP4 4                           // cbsz/blgp encoding for fp4 e2m1

// e2m1 encode of |v|<=~6 with round-to-nearest. Values: 0,.5,1,1.5,2,3,4,6.
static __device__ inline unsigned fp4_enc(float v) {
    const unsigned s = (__float_as_uint(v) >> 28) & 8u;   // sign -> bit3
    const float a = fabsf(v);
    unsigned c;
    if      (a < 0.25f) c = 0;
    else if (a < 0.75f) c = 1;
    else if (a < 1.25f) c = 2;
    else if (a < 1.75f) c = 3;
    else if (a < 2.5f)  c = 4;
    else if (a < 3.5f)  c = 5;
    else if (a < 5.0f)  c = 6;
    else                c = 7;
    return s | c;
}

// ---------------------------------------------------------------------------
// Kernel 1: L2-normalize pairs; write z4 = fp4_e2m1(32 * z) (element k at
// nibble k: even k low nibble) and fp32 pos[i] = cos(z_i, z_{i+B})/TEMP.
// Thread t owns elements 2t,2t+1 -> exactly byte t of the 256-B row.
// Also zeroes out[0] (stream-ordered before lse_kernel's atomicAdd).
// ---------------------------------------------------------------------------
__global__ __launch_bounds__(256) void norm_kernel(
    const float* __restrict__ p1, const float* __restrict__ p2,
    unsigned char* __restrict__ z4, float* __restrict__ pos,
    float* __restrict__ out)
{
    const int i = blockIdx.x;          // 0..4095
    const int t = threadIdx.x;         // 0..255
    const int wave = t >> 6, lane = t & 63;

    if (i == 0 && t == 0) out[0] = 0.0f;   // atomic accumulator init

    const float2 xv = ((const float2*)(p1 + (size_t)i * DIM))[t];
    const float2 yv = ((const float2*)(p2 + (size_t)i * DIM))[t];

    float sx = fmaf(xv.x, xv.x, xv.y * xv.y);
    float sy = fmaf(yv.x, yv.x, yv.y * yv.y);
    float sd = fmaf(xv.x, yv.x, xv.y * yv.y);

    #pragma unroll
    for (int off = 32; off > 0; off >>= 1) {
        sx += __shfl_down(sx, off);
        sy += __shfl_down(sy, off);
        sd += __shfl_down(sd, off);
    }

    __shared__ float red[3][4];
    if (lane == 0) { red[0][wave] = sx; red[1][wave] = sy; red[2][wave] = sd; }
    __syncthreads();
    sx = red[0][0] + red[0][1] + red[0][2] + red[0][3];
    sy = red[1][0] + red[1][1] + red[1][2] + red[1][3];
    sd = red[2][0] + red[2][1] + red[2][2] + red[2][3];

    const float rx = 1.0f / fmaxf(sqrtf(sx), 1e-12f);
    const float ry = 1.0f / fmaxf(sqrtf(sy), 1e-12f);
    const float gx = 32.0f * rx, gy = 32.0f * ry;   // x32 -> sigma ~1.4 in fp4

    z4[(size_t)i * DIMB + t] =
        (unsigned char)(fp4_enc(xv.x * gx) | (fp4_enc(xv.y * gx) << 4));
    z4[(size_t)(i + BATCH) * DIMB + t] =
        (unsigned char)(fp4_enc(yv.x * gy) | (fp4_enc(yv.y * gy) << 4));

    if (t == 0) pos[i] = sd * rx * ry * INV_T;
}

// ---------------------------------------------------------------------------
// Kernel 2: UPPER-TRIANGLE fused z@z^T tiles in MX-FP4, double-buffered LDS.
// mfma_scale_f32_32x32x64_f8f6f4 (cbsz=blgp=4 -> fp4 e2m1), scale 2^-5 both
// operands. 128x128 tile, BK=64 elements (32 B/row), 8 K-iters, one barrier
// per iter with next-slab prefetch in flight across the compute phase.
//
// LDS slab: 128 rows x 2 chunks of 16 B. Physical chunk for (row m, chunk c):
//   q = (m>>2)*8 + ((((m&3)*2) + c) ^ ((m>>2)&7))
// Inverse (staged by thread p): g=p>>3, w=(p&7)^(g&7), m=g*4+(w>>1), c=w&1.
// Frag reads (1 b128/lane per matrix-subtile) hit all 8 bank-groups per 8
// consecutive rows -> exactly 8 phases per wave access (the b128 floor).
//
// A/B frag (fp4 ext of verified fp8 layout): m = lane&31,
// k = (lane>>5)*32 + j, element j at nibble j of the lane's 16 B.
// Epilogue identical to round 6 (C/D layout shape-determined).
// ---------------------------------------------------------------------------
__global__ __launch_bounds__(256) void sim_kernel(
    const unsigned char* __restrict__ z4, float* __restrict__ partial)
{
    // staging: buf0 [0,8192) = A[0,4096)|B[4096,8192); buf1 [8192,16384)
    // epilogue: rowbuf[64][68] f32 [0,17408) aliases staging; colred separate.
    __shared__ __align__(16) unsigned char smem[19968];
    float* rowbuf = (float*)smem;               // [64][68]
    float* colred = (float*)(smem + 17408);     // [128*5]

    // --- triangular decode: blockIdx.x -> (rt, ct), rt <= ct --------------
    const int idx = blockIdx.x;
    int rt = (int)((129.0 - sqrt(16641.0 - 8.0 * (double)idx)) * 0.5);
    while (64 * (rt + 1) - ((rt + 1) * rt) / 2 <= idx) ++rt;
    while (64 * rt - (rt * (rt - 1)) / 2 > idx) --rt;
    const int ct = rt + (idx - (64 * rt - (rt * (rt - 1)) / 2));
    const bool diag = (rt == ct);

    const int t = threadIdx.x;
    const int wave = t >> 6, lane = t & 63;
    const int wr = wave >> 1, wc = wave & 1;   // 2x2 wave grid, 64x64 each
    const int lrow  = lane & 31;               // m/n within a 32-tile
    const int lhalf = lane >> 5;               // k-half selector (chunk c)

    const unsigned char* Ag = z4 + (size_t)rt * 128 * DIMB;
    const unsigned char* Bg = z4 + (size_t)ct * 128 * DIMB;

    // Staging source byte-offset (loop-invariant): thread p=t fills physical
    // chunk p; decode (m,c) via the swizzle inverse.
    int src_off;
    {
        const int g = t >> 3, w = (t & 7) ^ (g & 7);
        const int m = g * 4 + (w >> 1), c = w & 1;
        src_off = m * DIMB + c * 16;
    }

    // Frag LDS byte-offsets within a slab (loop-invariant): row m, chunk lhalf.
    int offA[2], offB[2];
    #pragma unroll
    for (int mi = 0; mi < 2; ++mi) {
        {
            const int m = wr * 64 + mi * 32 + lrow;
            offA[mi] = ((m >> 2) * 8 + ((((m & 3) * 2) + lhalf) ^ ((m >> 2) & 7))) * 16;
        }
        {
            const int m = wc * 64 + mi * 32 + lrow;
            offB[mi] = ((m >> 2) * 8 + ((((m & 3) * 2) + lhalf) ^ ((m >> 2) & 7))) * 16;
        }
    }

    floatx16 acc[2][2];
    #pragma unroll
    for (int mi = 0; mi < 2; ++mi)
        #pragma unroll
        for (int ni = 0; ni < 2; ++ni)
            acc[mi][ni] = (floatx16)0.0f;

    // Prologue: stage k=0 slab into buf0.
    {
        unsigned char* dst = smem + wave * 1024;
        __builtin_amdgcn_global_load_lds(AS1(Ag + src_off), AS3(dst), 16, 0, 0);
        if (!diag)
            __builtin_amdgcn_global_load_lds(AS1(Bg + src_off), AS3(dst + 4096),
                                             16, 0, 0);
    }

    for (int k = 0; k < 8; ++k) {
        __syncthreads();   // drains stage of buf[k&1]; WAR-protects buf[(k+1)&1]

        if (k < 7) {       // prefetch next K-slab (32 B/row further)
            unsigned char* dst = smem + ((k + 1) & 1) * 8192 + wave * 1024;
            const int kb = (k + 1) * 32;
            __builtin_amdgcn_global_load_lds(AS1(Ag + kb + src_off), AS3(dst),
                                             16, 0, 0);
            if (!diag)
                __builtin_amdgcn_global_load_lds(AS1(Bg + kb + src_off),
                                                 AS3(dst + 4096), 16, 0, 0);
        }

        const unsigned char* Ab = smem + (k & 1) * 8192;
        const unsigned char* Bb = diag ? Ab : Ab + 4096;

        intx8 af[2], bf[2];
        #pragma unroll
        for (int mi = 0; mi < 2; ++mi) {
            const intx4 a0 = *(const intx4*)(Ab + offA[mi]);
            const intx4 b0 = *(const intx4*)(Bb + offB[mi]);
            #pragma unroll
            for (int j = 0; j < 4; ++j) {
                af[mi][j] = a0[j]; af[mi][j + 4] = 0;
                bf[mi][j] = b0[j]; bf[mi][j + 4] = 0;
            }
        }

        #pragma unroll
        for (int mi = 0; mi < 2; ++mi)
            #pragma unroll
            for (int ni = 0; ni < 2; ++ni)
                acc[mi][ni] = __builtin_amdgcn_mfma_scale_f32_32x32x64_f8f6f4(
                    af[mi], bf[ni], acc[mi][ni],
                    FMT_FP4, FMT_FP4,           // cbsz, blgp = fp4 e2m1
                    0, SCALE_E8M0,              // opsel_a, scale_a (2^-5)
                    0, SCALE_E8M0);             // opsel_b, scale_b (2^-5)
    }

    // --- epilogue ----------------------------------------------------------
    // C/D layout (shape-determined, m74/m101/m121-128): col = lane&31,
    // row = (reg&3) + 8*(reg>>2) + 4*(lane>>5), within each 32x32 tile.
    float cs[2] = {0.0f, 0.0f};     // per-column sums (2 cols this lane owns)
    float rw[2][16];                // per-row partials (summed over ni in-lane)
    #pragma unroll
    for (int mi = 0; mi < 2; ++mi)
        #pragma unroll
        for (int r = 0; r < 16; ++r)
            rw[mi][r] = 0.0f;

    #pragma unroll
    for (int mi = 0; mi < 2; ++mi) {
        #pragma unroll
        for (int ni = 0; ni < 2; ++ni) {
            const int col_l = wc * 64 + ni * 32 + lrow;
            #pragma unroll
            for (int r = 0; r < 16; ++r) {
                const int row_l = wr * 64 + mi * 32 + lhalf * 4 + (r & 3) + 8 * (r >> 2);
                float ee = __builtin_amdgcn_exp2f(acc[mi][ni][r] * LSE_SCALE);
                if (diag && (row_l == col_l)) ee = 0.0f;   // -inf self mask
                cs[ni] += ee;
                rw[mi][r] += ee;
            }
        }
    }

    // col sums -> colred (4 partials/column, stride-5; no staging alias)
    const int slot = wr * 2 + lhalf;
    #pragma unroll
    for (int ni = 0; ni < 2; ++ni)
        colred[(wc * 64 + ni * 32 + lrow) * 5 + slot] = cs[ni];

    __syncthreads();   // K-loop ds_reads done (rowbuf aliasing) + colred visible

    if (t < 128) {
        const float s = colred[t * 5 + 0] + colred[t * 5 + 1] +
                        colred[t * 5 + 2] + colred[t * 5 + 3];
        partial[(size_t)rt * TWO_B + (size_t)ct * 128 + t] = s;
    }

    if (!diag) {
        #pragma unroll
        for (int p = 0; p < 2; ++p) {
            if (wr == p) {
                #pragma unroll
                for (int mi = 0; mi < 2; ++mi)
                    #pragma unroll
                    for (int r = 0; r < 16; ++r) {
                        const int lr = mi * 32 + lhalf * 4 + (r & 3) + 8 * (r >> 2);
                        rowbuf[lr * 68 + wc * 32 + lrow] = rw[mi][r];
                    }
            }
            __syncthreads();
            if (t < 128) {
                const int r = t >> 1, h = t & 1;
                const float4* rb = (const float4*)(rowbuf + r * 68 + h * 32);
                float s = 0.0f;
                #pragma unroll
                for (int j = 0; j < 8; ++j) {
                    const float4 v = rb[j];
                    s += (v.x + v.y) + (v.z + v.w);
                }
                s += __shfl_xor(s, 1, 64);     // combine the two half-rows
                if (h == 0)
                    partial[(size_t)ct * TWO_B + (size_t)rt * 128 + p * 64 + r] = s;
            }
            if (p == 0) __syncthreads();       // phase-0 reads before phase-1 writes
        }
    }
}

// ---------------------------------------------------------------------------
// Kernel 3: per-row sumexp over 64 tile contributions -> lse - pos term,
// block-reduced, atomically accumulated into out.
// ---------------------------------------------------------------------------
__global__ __launch_bounds__(256) void lse_kernel(
    const float* __restrict__ partial, const float* __restrict__ pos,
    float* __restrict__ out)
{
    const int t = threadIdx.x;
    const int row = blockIdx.x * 256 + t;
    float s = 0.0f;
    #pragma unroll 8
    for (int tile = 0; tile < 64; ++tile)
        s += partial[(size_t)tile * TWO_B + row];
    float term = logf(s) - pos[row & (BATCH - 1)];   // sim_ij == sim_ji

    #pragma unroll
    for (int off = 32; off > 0; off >>= 1)
        term += __shfl_down(term, off);
    __shared__ float wsum[4];
    if ((t & 63) == 0) wsum[t >> 6] = term;
    __syncthreads();
    if (t == 0)
        atomicAdd(out, (wsum[0] + wsum[1] + wsum[2] + wsum[3]) *
                       (1.0f / (float)TWO_B));
}

// ---------------------------------------------------------------------------
extern "C" void kernel_launch(void* const* d_in, const int* in_sizes, int n_in,
                              void* d_out, int out_size, void* d_ws, size_t ws_size,
                              hipStream_t stream)
{
    const float* p1 = (const float*)d_in[0];
    const float* p2 = (const float*)d_in[1];
    float* out = (float*)d_out;

    // Workspace layout (all fully rewritten every call; poison-safe):
    //   z4       : 8192*256 fp4   = 2,097,152 B
    //   pos      : 4096 f32       =    16,384 B
    //   partial  : 64*8192 f32    = 2,097,152 B
    char* ws = (char*)d_ws;
    unsigned char* z4  = (unsigned char*)ws;
    float* pos         = (float*)(ws + 2097152);
    float* partial     = (float*)(ws + 2097152 + 16384);

    norm_kernel<<<BATCH, 256, 0, stream>>>(p1, p2, z4, pos, out);
    sim_kernel<<<NTRI, 256, 0, stream>>>(z4, partial);
    lse_kernel<<<32, 256, 0, stream>>>(partial, pos, out);
}

// Round 8
// 96.422 us; speedup vs baseline: 1.2856x; 1.0175x over previous
//
#include <hip/hip_runtime.h>
#include <hip/hip_bf16.h>
#include <math.h>

// Problem constants
#define BATCH   4096
#define DIM     512
#define DIMB    256                         // bytes per z4 row (fp4 = nibble)
#define TWO_B   8192
#define INV_T   10.0f                       // 1/TEMP
#define LSE_SCALE 14.426950408889634f       // log2(e)/TEMP
#define NTRI    2080                        // 64*65/2 upper-triangle tiles

typedef __attribute__((ext_vector_type(8)))  int   intx8;
typedef __attribute__((ext_vector_type(4)))  int   intx4;
typedef __attribute__((ext_vector_type(16))) float floatx16; // 32x32 MFMA acc

#define AS1(p) ((__attribute__((address_space(1))) void*)(p))
#define AS3(p) ((__attribute__((address_space(3))) void*)(p))

// E8M0 scale byte: 2^(x-127). 122 -> 2^-5 per operand (z stored x32; 2^-10
// total undoes 32*32).
#define SCALE_E8M0 122
#define FMT_FP4 4                           // cbsz/blgp encoding for fp4 e2m1

// e2m1 encode of |v|<=~6 with round-to-nearest. Values: 0,.5,1,1.5,2,3,4,6.
static __device__ inline unsigned fp4_enc(float v) {
    const unsigned s = (__float_as_uint(v) >> 28) & 8u;   // sign -> bit3
    const float a = fabsf(v);
    unsigned c;
    if      (a < 0.25f) c = 0;
    else if (a < 0.75f) c = 1;
    else if (a < 1.25f) c = 2;
    else if (a < 1.75f) c = 3;
    else if (a < 2.5f)  c = 4;
    else if (a < 3.5f)  c = 5;
    else if (a < 5.0f)  c = 6;
    else                c = 7;
    return s | c;
}

// ---------------------------------------------------------------------------
// Kernel 1: L2-normalize pairs; write z4 = fp4_e2m1(32 * z) (element k at
// nibble k) and fp32 pos[i] = cos(z_i, z_{i+B})/TEMP. Thread t owns elements
// 2t,2t+1 -> byte t of the 256-B row. Also zeroes out[0].
// ---------------------------------------------------------------------------
__global__ __launch_bounds__(256) void norm_kernel(
    const float* __restrict__ p1, const float* __restrict__ p2,
    unsigned char* __restrict__ z4, float* __restrict__ pos,
    float* __restrict__ out)
{
    const int i = blockIdx.x;          // 0..4095
    const int t = threadIdx.x;         // 0..255
    const int wave = t >> 6, lane = t & 63;

    if (i == 0 && t == 0) out[0] = 0.0f;   // atomic accumulator init

    const float2 xv = ((const float2*)(p1 + (size_t)i * DIM))[t];
    const float2 yv = ((const float2*)(p2 + (size_t)i * DIM))[t];

    float sx = fmaf(xv.x, xv.x, xv.y * xv.y);
    float sy = fmaf(yv.x, yv.x, yv.y * yv.y);
    float sd = fmaf(xv.x, yv.x, xv.y * yv.y);

    #pragma unroll
    for (int off = 32; off > 0; off >>= 1) {
        sx += __shfl_down(sx, off);
        sy += __shfl_down(sy, off);
        sd += __shfl_down(sd, off);
    }

    __shared__ float red[3][4];
    if (lane == 0) { red[0][wave] = sx; red[1][wave] = sy; red[2][wave] = sd; }
    __syncthreads();
    sx = red[0][0] + red[0][1] + red[0][2] + red[0][3];
    sy = red[1][0] + red[1][1] + red[1][2] + red[1][3];
    sd = red[2][0] + red[2][1] + red[2][2] + red[2][3];

    const float rx = 1.0f / fmaxf(sqrtf(sx), 1e-12f);
    const float ry = 1.0f / fmaxf(sqrtf(sy), 1e-12f);
    const float gx = 32.0f * rx, gy = 32.0f * ry;   // x32 -> sigma ~1.4 in fp4

    z4[(size_t)i * DIMB + t] =
        (unsigned char)(fp4_enc(xv.x * gx) | (fp4_enc(xv.y * gx) << 4));
    z4[(size_t)(i + BATCH) * DIMB + t] =
        (unsigned char)(fp4_enc(yv.x * gy) | (fp4_enc(yv.y * gy) << 4));

    if (t == 0) pos[i] = sd * rx * ry * INV_T;
}

// ---------------------------------------------------------------------------
// Kernel 2: UPPER-TRIANGLE fused z@z^T tiles in MX-FP4, FULL-K staging.
// The entire 128x512 fp4 tile is 32 KB, so A and B are staged completely
// (16 global_load_lds/thread), then ONE barrier, then 32 MFMA + 32 b128
// frag reads with NO further vmcnt-drain barriers. This removes the per-
// K-iter barrier stall that dominated rounds 5-7.
//
// LDS: A slabs [0,32K) = 8 x 4 KB (one per K-slab of 64 elems), B slabs
// [32K,64K). Within a slab, physical 16B-chunk for (row m, chunk c):
//   q = (m>>2)*8 + ((((m&3)*2) + c) ^ ((m>>2)&7))     (c = 0,1)
// Inverse (staged by thread p): g=p>>3, w=(p&7)^(g&7), m=g*4+(w>>1), c=w&1.
//
// A/B frag (fp4): m = lane&31, k = (lane>>5)*32 + j, elem j at nibble j.
// Diagonal tiles stage A only (B frags read from A region).
// Epilogue: exp2 + diag mask; colsum in-lane; rowsum via 2-phase LDS
// transpose. rowbuf/colred alias the (dead) staging buffers post-barrier.
// ---------------------------------------------------------------------------
__global__ __launch_bounds__(256) void sim_kernel(
    const unsigned char* __restrict__ z4, float* __restrict__ partial)
{
    __shared__ __align__(16) unsigned char smem[65536];
    float* rowbuf = (float*)smem;               // [64][68] f32, aliases A slabs
    float* colred = (float*)(smem + 32768);     // [128*5] f32, aliases B slabs

    // --- triangular decode: blockIdx.x -> (rt, ct), rt <= ct --------------
    const int idx = blockIdx.x;
    int rt = (int)((129.0 - sqrt(16641.0 - 8.0 * (double)idx)) * 0.5);
    while (64 * (rt + 1) - ((rt + 1) * rt) / 2 <= idx) ++rt;
    while (64 * rt - (rt * (rt - 1)) / 2 > idx) --rt;
    const int ct = rt + (idx - (64 * rt - (rt * (rt - 1)) / 2));
    const bool diag = (rt == ct);

    const int t = threadIdx.x;
    const int wave = t >> 6, lane = t & 63;
    const int wr = wave >> 1, wc = wave & 1;   // 2x2 wave grid, 64x64 each
    const int lrow  = lane & 31;               // m/n within a 32-tile
    const int lhalf = lane >> 5;               // k-half selector (chunk c)

    const unsigned char* Ag = z4 + (size_t)rt * 128 * DIMB;
    const unsigned char* Bg = z4 + (size_t)ct * 128 * DIMB;

    // Staging source byte-offset (swizzle inverse): thread t fills physical
    // chunk t of each slab.
    int src_off;
    {
        const int g = t >> 3, w = (t & 7) ^ (g & 7);
        const int m = g * 4 + (w >> 1), c = w & 1;
        src_off = m * DIMB + c * 16;
    }

    // Frag LDS byte-offsets within a slab (loop-invariant): row m, chunk lhalf.
    int offA[2], offB[2];
    #pragma unroll
    for (int mi = 0; mi < 2; ++mi) {
        {
            const int m = wr * 64 + mi * 32 + lrow;
            offA[mi] = ((m >> 2) * 8 + ((((m & 3) * 2) + lhalf) ^ ((m >> 2) & 7))) * 16;
        }
        {
            const int m = wc * 64 + mi * 32 + lrow;
            offB[mi] = ((m >> 2) * 8 + ((((m & 3) * 2) + lhalf) ^ ((m >> 2) & 7))) * 16;
        }
    }

    // --- stage the FULL K extent of A (and B) ------------------------------
    {
        unsigned char* dstA = smem + wave * 1024;
        #pragma unroll
        for (int s = 0; s < 8; ++s)
            __builtin_amdgcn_global_load_lds(AS1(Ag + s * 32 + src_off),
                                             AS3(dstA + s * 4096), 16, 0, 0);
        if (!diag) {
            unsigned char* dstB = smem + 32768 + wave * 1024;
            #pragma unroll
            for (int s = 0; s < 8; ++s)
                __builtin_amdgcn_global_load_lds(AS1(Bg + s * 32 + src_off),
                                                 AS3(dstB + s * 4096), 16, 0, 0);
        }
    }
    __syncthreads();   // the ONLY vmcnt-drain barrier in the kernel

    // --- barrier-free compute over all 8 K-slabs ---------------------------
    floatx16 acc[2][2];
    #pragma unroll
    for (int mi = 0; mi < 2; ++mi)
        #pragma unroll
        for (int ni = 0; ni < 2; ++ni)
            acc[mi][ni] = (floatx16)0.0f;

    const unsigned char* Abase = smem;
    const unsigned char* Bbase = diag ? smem : smem + 32768;

    #pragma unroll
    for (int s = 0; s < 8; ++s) {
        const unsigned char* Ab = Abase + s * 4096;
        const unsigned char* Bb = Bbase + s * 4096;
        intx8 af[2], bf[2];
        #pragma unroll
        for (int mi = 0; mi < 2; ++mi) {
            const intx4 a0 = *(const intx4*)(Ab + offA[mi]);
            const intx4 b0 = *(const intx4*)(Bb + offB[mi]);
            #pragma unroll
            for (int j = 0; j < 4; ++j) {
                af[mi][j] = a0[j]; af[mi][j + 4] = 0;
                bf[mi][j] = b0[j]; bf[mi][j + 4] = 0;
            }
        }
        #pragma unroll
        for (int mi = 0; mi < 2; ++mi)
            #pragma unroll
            for (int ni = 0; ni < 2; ++ni)
                acc[mi][ni] = __builtin_amdgcn_mfma_scale_f32_32x32x64_f8f6f4(
                    af[mi], bf[ni], acc[mi][ni],
                    FMT_FP4, FMT_FP4,           // cbsz, blgp = fp4 e2m1
                    0, SCALE_E8M0,              // opsel_a, scale_a (2^-5)
                    0, SCALE_E8M0);             // opsel_b, scale_b (2^-5)
    }

    // --- epilogue ----------------------------------------------------------
    // C/D layout (shape-determined, m74/m101/m121-128): col = lane&31,
    // row = (reg&3) + 8*(reg>>2) + 4*(lane>>5), within each 32x32 tile.
    float cs[2] = {0.0f, 0.0f};     // per-column sums (2 cols this lane owns)
    float rw[2][16];                // per-row partials (summed over ni in-lane)
    #pragma unroll
    for (int mi = 0; mi < 2; ++mi)
        #pragma unroll
        for (int r = 0; r < 16; ++r)
            rw[mi][r] = 0.0f;

    #pragma unroll
    for (int mi = 0; mi < 2; ++mi) {
        #pragma unroll
        for (int ni = 0; ni < 2; ++ni) {
            const int col_l = wc * 64 + ni * 32 + lrow;
            #pragma unroll
            for (int r = 0; r < 16; ++r) {
                const int row_l = wr * 64 + mi * 32 + lhalf * 4 + (r & 3) + 8 * (r >> 2);
                float ee = __builtin_amdgcn_exp2f(acc[mi][ni][r] * LSE_SCALE);
                if (diag && (row_l == col_l)) ee = 0.0f;   // -inf self mask
                cs[ni] += ee;
                rw[mi][r] += ee;
            }
        }
    }

    __syncthreads();   // all frag ds_reads done before aliasing writes below

    // col sums -> colred (4 partials/column, stride-5)
    const int slot = wr * 2 + lhalf;
    #pragma unroll
    for (int ni = 0; ni < 2; ++ni)
        colred[(wc * 64 + ni * 32 + lrow) * 5 + slot] = cs[ni];

    __syncthreads();

    if (t < 128) {
        const float s = colred[t * 5 + 0] + colred[t * 5 + 1] +
                        colred[t * 5 + 2] + colred[t * 5 + 3];
        partial[(size_t)rt * TWO_B + (size_t)ct * 128 + t] = s;
    }

    if (!diag) {
        #pragma unroll
        for (int p = 0; p < 2; ++p) {
            if (wr == p) {
                #pragma unroll
                for (int mi = 0; mi < 2; ++mi)
                    #pragma unroll
                    for (int r = 0; r < 16; ++r) {
                        const int lr = mi * 32 + lhalf * 4 + (r & 3) + 8 * (r >> 2);
                        rowbuf[lr * 68 + wc * 32 + lrow] = rw[mi][r];
                    }
            }
            __syncthreads();
            if (t < 128) {
                const int r = t >> 1, h = t & 1;
                const float4* rb = (const float4*)(rowbuf + r * 68 + h * 32);
                float s = 0.0f;
                #pragma unroll
                for (int j = 0; j < 8; ++j) {
                    const float4 v = rb[j];
                    s += (v.x + v.y) + (v.z + v.w);
                }
                s += __shfl_xor(s, 1, 64);     // combine the two half-rows
                if (h == 0)
                    partial[(size_t)ct * TWO_B + (size_t)rt * 128 + p * 64 + r] = s;
            }
            if (p == 0) __syncthreads();       // phase-0 reads before phase-1 writes
        }
    }
}

// ---------------------------------------------------------------------------
// Kernel 3: per-row sumexp over 64 tile contributions -> lse - pos term,
// block-reduced, atomically accumulated into out.
// ---------------------------------------------------------------------------
__global__ __launch_bounds__(256) void lse_kernel(
    const float* __restrict__ partial, const float* __restrict__ pos,
    float* __restrict__ out)
{
    const int t = threadIdx.x;
    const int row = blockIdx.x * 256 + t;
    float s = 0.0f;
    #pragma unroll 8
    for (int tile = 0; tile < 64; ++tile)
        s += partial[(size_t)tile * TWO_B + row];
    float term = logf(s) - pos[row & (BATCH - 1)];   // sim_ij == sim_ji

    #pragma unroll
    for (int off = 32; off > 0; off >>= 1)
        term += __shfl_down(term, off);
    __shared__ float wsum[4];
    if ((t & 63) == 0) wsum[t >> 6] = term;
    __syncthreads();
    if (t == 0)
        atomicAdd(out, (wsum[0] + wsum[1] + wsum[2] + wsum[3]) *
                       (1.0f / (float)TWO_B));
}

// ---------------------------------------------------------------------------
extern "C" void kernel_launch(void* const* d_in, const int* in_sizes, int n_in,
                              void* d_out, int out_size, void* d_ws, size_t ws_size,
                              hipStream_t stream)
{
    const float* p1 = (const float*)d_in[0];
    const float* p2 = (const float*)d_in[1];
    float* out = (float*)d_out;

    // Workspace layout (all fully rewritten every call; poison-safe):
    //   z4       : 8192*256 fp4   = 2,097,152 B
    //   pos      : 4096 f32       =    16,384 B
    //   partial  : 64*8192 f32    = 2,097,152 B
    char* ws = (char*)d_ws;
    unsigned char* z4  = (unsigned char*)ws;
    float* pos         = (float*)(ws + 2097152);
    float* partial     = (float*)(ws + 2097152 + 16384);

    norm_kernel<<<BATCH, 256, 0, stream>>>(p1, p2, z4, pos, out);
    sim_kernel<<<NTRI, 256, 0, stream>>>(z4, partial);
    lse_kernel<<<32, 256, 0, stream>>>(partial, pos, out);
}

// Round 9
// 90.729 us; speedup vs baseline: 1.3663x; 1.0627x over previous
//
#include <hip/hip_runtime.h>
#include <hip/hip_bf16.h>
#include <math.h>

// Problem constants
#define BATCH   4096
#define DIM     512
#define DIMB    256                         // bytes per fp4 row
#define TWO_B   8192
#define INV_T   10.0f                       // 1/TEMP
#define LSE_SCALE 14.426950408889634f       // log2(e)/TEMP
#define NTRI    2080                        // 64*65/2 upper-triangle tiles

typedef __attribute__((ext_vector_type(8)))  int   intx8;
typedef __attribute__((ext_vector_type(4)))  int   intx4;
typedef __attribute__((ext_vector_type(16))) float floatx16; // 32x32 MFMA acc

// E8M0 scale byte: 2^(x-127). 122 -> 2^-5 per operand (z stored x32; 2^-10
// total undoes 32*32).
#define SCALE_E8M0 122
#define FMT_FP4 4                           // cbsz/blgp encoding for fp4 e2m1

// e2m1 encode of |v|<=~6 with round-to-nearest. Values: 0,.5,1,1.5,2,3,4,6.
static __device__ inline unsigned fp4_enc(float v) {
    const unsigned s = (__float_as_uint(v) >> 28) & 8u;   // sign -> bit3
    const float a = fabsf(v);
    unsigned c;
    if      (a < 0.25f) c = 0;
    else if (a < 0.75f) c = 1;
    else if (a < 1.25f) c = 2;
    else if (a < 1.75f) c = 3;
    else if (a < 2.5f)  c = 4;
    else if (a < 3.5f)  c = 5;
    else if (a < 5.0f)  c = 6;
    else                c = 7;
    return s | c;
}

// Fragment-order z4 layout ("tiled"): for global row R and row-byte t
// (elements 2t,2t+1), the byte lives at
//   (R>>5)*8192 + (t>>5)*1024 + ((t>>4)&1)*512 + (R&31)*16 + (t&15)
// so that an MFMA A/B fragment load (row-block rb, slab s, lane = r + 32*c)
// is ONE contiguous 1 KB segment: rb*8192 + s*1024 + c*512 + r*16.
static __device__ inline size_t z4t_addr(int R, int t) {
    return (size_t)(R >> 5) * 8192 + (size_t)(t >> 5) * 1024 +
           (size_t)((t >> 4) & 1) * 512 + (size_t)(R & 31) * 16 + (t & 15);
}

// ---------------------------------------------------------------------------
// Kernel 1: L2-normalize pairs; write z4t = fp4_e2m1(32 * z) in fragment
// order, and fp32 pos[i] = cos(z_i, z_{i+B})/TEMP. Thread t owns elements
// 2t,2t+1 (= row-byte t). Also zeroes out[0].
// ---------------------------------------------------------------------------
__global__ __launch_bounds__(256) void norm_kernel(
    const float* __restrict__ p1, const float* __restrict__ p2,
    unsigned char* __restrict__ z4, float* __restrict__ pos,
    float* __restrict__ out)
{
    const int i = blockIdx.x;          // 0..4095
    const int t = threadIdx.x;         // 0..255
    const int wave = t >> 6, lane = t & 63;

    if (i == 0 && t == 0) out[0] = 0.0f;   // atomic accumulator init

    const float2 xv = ((const float2*)(p1 + (size_t)i * DIM))[t];
    const float2 yv = ((const float2*)(p2 + (size_t)i * DIM))[t];

    float sx = fmaf(xv.x, xv.x, xv.y * xv.y);
    float sy = fmaf(yv.x, yv.x, yv.y * yv.y);
    float sd = fmaf(xv.x, yv.x, xv.y * yv.y);

    #pragma unroll
    for (int off = 32; off > 0; off >>= 1) {
        sx += __shfl_down(sx, off);
        sy += __shfl_down(sy, off);
        sd += __shfl_down(sd, off);
    }

    __shared__ float red[3][4];
    if (lane == 0) { red[0][wave] = sx; red[1][wave] = sy; red[2][wave] = sd; }
    __syncthreads();
    sx = red[0][0] + red[0][1] + red[0][2] + red[0][3];
    sy = red[1][0] + red[1][1] + red[1][2] + red[1][3];
    sd = red[2][0] + red[2][1] + red[2][2] + red[2][3];

    const float rx = 1.0f / fmaxf(sqrtf(sx), 1e-12f);
    const float ry = 1.0f / fmaxf(sqrtf(sy), 1e-12f);
    const float gx = 32.0f * rx, gy = 32.0f * ry;   // x32 -> sigma ~1.4 in fp4

    z4[z4t_addr(i, t)] =
        (unsigned char)(fp4_enc(xv.x * gx) | (fp4_enc(xv.y * gx) << 4));
    z4[z4t_addr(i + BATCH, t)] =
        (unsigned char)(fp4_enc(yv.x * gy) | (fp4_enc(yv.y * gy) << 4));

    if (t == 0) pos[i] = sd * rx * ry * INV_T;
}

// ---------------------------------------------------------------------------
// Kernel 2: UPPER-TRIANGLE fused z@z^T tiles in MX-FP4, LDS-FREE K-loop.
// Fragments are gathered DIRECTLY from the fragment-ordered z4t (one fully
// coalesced 1 KB global_load_dwordx4 per wave per fragment) — no LDS
// staging, no ds_read, NO barriers in the K-loop at all. z4t is 2 MB ->
// L2-resident per XCD; per-wave independent load streams + MFMA overlap
// via normal vmcnt scheduling (the AITER-style pipeline the barrier
// structure could never express).
//
// A/B frag (fp4): m = lane&31, k = (lane>>5)*32 + j, elem j at nibble j.
// 128x128 tile per block, 2x2 waves of 64x64 (2x2 of 32x32 MFMA).
// Epilogue: exp2 + diag mask; colsum in-lane; rowsum via 2-phase LDS
// transpose (20 KB LDS, epilogue only). partial[rt][ct*128+j] (colsums)
// and partial[ct][rt*128+i] (rowsums); every slot written exactly once.
// ---------------------------------------------------------------------------
__global__ __launch_bounds__(256, 3) void sim_kernel(
    const unsigned char* __restrict__ z4, float* __restrict__ partial)
{
    __shared__ __align__(16) unsigned char smem[19968];
    float* rowbuf = (float*)smem;               // [64][68] f32
    float* colred = (float*)(smem + 17408);     // [128*5] f32

    // --- triangular decode: blockIdx.x -> (rt, ct), rt <= ct --------------
    const int idx = blockIdx.x;
    int rt = (int)((129.0 - sqrt(16641.0 - 8.0 * (double)idx)) * 0.5);
    while (64 * (rt + 1) - ((rt + 1) * rt) / 2 <= idx) ++rt;
    while (64 * rt - (rt * (rt - 1)) / 2 > idx) --rt;
    const int ct = rt + (idx - (64 * rt - (rt * (rt - 1)) / 2));
    const bool diag = (rt == ct);

    const int t = threadIdx.x;
    const int wave = t >> 6, lane = t & 63;
    const int wr = wave >> 1, wc = wave & 1;   // 2x2 wave grid, 64x64 each
    const int lrow  = lane & 31;               // m/n within a 32-tile
    const int lhalf = lane >> 5;               // k-half (chunk) selector

    // Per-lane byte offset within a (row-block, slab) 1 KB segment.
    const int loff = lhalf * 512 + lrow * 16;
    // Row-block bases: row-block index = tile*4 + w*2 + mi.
    const unsigned char* Abase = z4 + (size_t)(rt * 4 + wr * 2) * 8192 + loff;
    const unsigned char* Bbase = z4 + (size_t)(ct * 4 + wc * 2) * 8192 + loff;

    floatx16 acc[2][2];
    #pragma unroll
    for (int mi = 0; mi < 2; ++mi)
        #pragma unroll
        for (int ni = 0; ni < 2; ++ni)
            acc[mi][ni] = (floatx16)0.0f;

    // --- barrier-free K-loop: 8 slabs x 4 frag gathers x 4 MFMA -----------
    #pragma unroll
    for (int s = 0; s < 8; ++s) {
        intx8 af[2], bf[2];
        #pragma unroll
        for (int mi = 0; mi < 2; ++mi) {
            const intx4 a0 = *(const intx4*)(Abase + mi * 8192 + s * 1024);
            const intx4 b0 = *(const intx4*)(Bbase + mi * 8192 + s * 1024);
            #pragma unroll
            for (int j = 0; j < 4; ++j) {
                af[mi][j] = a0[j]; af[mi][j + 4] = 0;
                bf[mi][j] = b0[j]; bf[mi][j + 4] = 0;
            }
        }
        #pragma unroll
        for (int mi = 0; mi < 2; ++mi)
            #pragma unroll
            for (int ni = 0; ni < 2; ++ni)
                acc[mi][ni] = __builtin_amdgcn_mfma_scale_f32_32x32x64_f8f6f4(
                    af[mi], bf[ni], acc[mi][ni],
                    FMT_FP4, FMT_FP4,           // cbsz, blgp = fp4 e2m1
                    0, SCALE_E8M0,              // opsel_a, scale_a (2^-5)
                    0, SCALE_E8M0);             // opsel_b, scale_b (2^-5)
    }

    // --- epilogue ----------------------------------------------------------
    // C/D layout (shape-determined, m74/m101/m121-128): col = lane&31,
    // row = (reg&3) + 8*(reg>>2) + 4*(lane>>5), within each 32x32 tile.
    float cs[2] = {0.0f, 0.0f};     // per-column sums (2 cols this lane owns)
    float rw[2][16];                // per-row partials (summed over ni in-lane)
    #pragma unroll
    for (int mi = 0; mi < 2; ++mi)
        #pragma unroll
        for (int r = 0; r < 16; ++r)
            rw[mi][r] = 0.0f;

    #pragma unroll
    for (int mi = 0; mi < 2; ++mi) {
        #pragma unroll
        for (int ni = 0; ni < 2; ++ni) {
            const int col_l = wc * 64 + ni * 32 + lrow;
            #pragma unroll
            for (int r = 0; r < 16; ++r) {
                const int row_l = wr * 64 + mi * 32 + lhalf * 4 + (r & 3) + 8 * (r >> 2);
                float ee = __builtin_amdgcn_exp2f(acc[mi][ni][r] * LSE_SCALE);
                if (diag && (row_l == col_l)) ee = 0.0f;   // -inf self mask
                cs[ni] += ee;
                rw[mi][r] += ee;
            }
        }
    }

    // col sums -> colred (4 partials/column, stride-5); rowbuf phase-0 now.
    const int slot = wr * 2 + lhalf;
    #pragma unroll
    for (int ni = 0; ni < 2; ++ni)
        colred[(wc * 64 + ni * 32 + lrow) * 5 + slot] = cs[ni];
    if (!diag && wr == 0) {
        #pragma unroll
        for (int mi = 0; mi < 2; ++mi)
            #pragma unroll
            for (int r = 0; r < 16; ++r) {
                const int lr = mi * 32 + lhalf * 4 + (r & 3) + 8 * (r >> 2);
                rowbuf[lr * 68 + wc * 32 + lrow] = rw[mi][r];
            }
    }
    __syncthreads();

    if (t < 128) {
        const float s = colred[t * 5 + 0] + colred[t * 5 + 1] +
                        colred[t * 5 + 2] + colred[t * 5 + 3];
        partial[(size_t)rt * TWO_B + (size_t)ct * 128 + t] = s;
    }

    if (!diag) {
        // phase-0 read (rows 0..63 of the tile)
        if (t < 128) {
            const int r = t >> 1, h = t & 1;
            const float4* rb = (const float4*)(rowbuf + r * 68 + h * 32);
            float s = 0.0f;
            #pragma unroll
            for (int j = 0; j < 8; ++j) {
                const float4 v = rb[j];
                s += (v.x + v.y) + (v.z + v.w);
            }
            s += __shfl_xor(s, 1, 64);
            if (h == 0)
                partial[(size_t)ct * TWO_B + (size_t)rt * 128 + r] = s;
        }
        __syncthreads();
        if (wr == 1) {                 // phase-1 write (rows 64..127)
            #pragma unroll
            for (int mi = 0; mi < 2; ++mi)
                #pragma unroll
                for (int r = 0; r < 16; ++r) {
                    const int lr = mi * 32 + lhalf * 4 + (r & 3) + 8 * (r >> 2);
                    rowbuf[lr * 68 + wc * 32 + lrow] = rw[mi][r];
                }
        }
        __syncthreads();
        if (t < 128) {
            const int r = t >> 1, h = t & 1;
            const float4* rb = (const float4*)(rowbuf + r * 68 + h * 32);
            float s = 0.0f;
            #pragma unroll
            for (int j = 0; j < 8; ++j) {
                const float4 v = rb[j];
                s += (v.x + v.y) + (v.z + v.w);
            }
            s += __shfl_xor(s, 1, 64);
            if (h == 0)
                partial[(size_t)ct * TWO_B + (size_t)rt * 128 + 64 + r] = s;
        }
    }
}

// ---------------------------------------------------------------------------
// Kernel 3: per-row sumexp over 64 tile contributions -> lse - pos term,
// block-reduced, atomically accumulated into out.
// ---------------------------------------------------------------------------
__global__ __launch_bounds__(256) void lse_kernel(
    const float* __restrict__ partial, const float* __restrict__ pos,
    float* __restrict__ out)
{
    const int t = threadIdx.x;
    const int row = blockIdx.x * 256 + t;
    float s = 0.0f;
    #pragma unroll 8
    for (int tile = 0; tile < 64; ++tile)
        s += partial[(size_t)tile * TWO_B + row];
    float term = logf(s) - pos[row & (BATCH - 1)];   // sim_ij == sim_ji

    #pragma unroll
    for (int off = 32; off > 0; off >>= 1)
        term += __shfl_down(term, off);
    __shared__ float wsum[4];
    if ((t & 63) == 0) wsum[t >> 6] = term;
    __syncthreads();
    if (t == 0)
        atomicAdd(out, (wsum[0] + wsum[1] + wsum[2] + wsum[3]) *
                       (1.0f / (float)TWO_B));
}

// ---------------------------------------------------------------------------
extern "C" void kernel_launch(void* const* d_in, const int* in_sizes, int n_in,
                              void* d_out, int out_size, void* d_ws, size_t ws_size,
                              hipStream_t stream)
{
    const float* p1 = (const float*)d_in[0];
    const float* p2 = (const float*)d_in[1];
    float* out = (float*)d_out;

    // Workspace layout (all fully rewritten every call; poison-safe):
    //   z4t      : 8192*256 fp4 (fragment-ordered) = 2,097,152 B
    //   pos      : 4096 f32                        =    16,384 B
    //   partial  : 64*8192 f32                     = 2,097,152 B
    char* ws = (char*)d_ws;
    unsigned char* z4  = (unsigned char*)ws;
    float* pos         = (float*)(ws + 2097152);
    float* partial     = (float*)(ws + 2097152 + 16384);

    norm_kernel<<<BATCH, 256, 0, stream>>>(p1, p2, z4, pos, out);
    sim_kernel<<<NTRI, 256, 0, stream>>>(z4, partial);
    lse_kernel<<<32, 256, 0, stream>>>(partial, pos, out);
}